// Round 14
// baseline (81.491 us; speedup 1.0000x reference)
//
#include <hip/hip_runtime.h>
#include <math.h>

#define NB 512      // graph pairs
#define MM 64       // nodes per graph
#define EPGc 512    // edges per graph

typedef __attribute__((ext_vector_type(8))) short s16x8;
typedef __attribute__((ext_vector_type(4))) float f32x4;

__device__ __forceinline__ unsigned short f2bf(float f) {
  union { float f; unsigned int u; } c; c.f = f;
  unsigned int u = c.u;
  return (unsigned short)((u + 0x7FFFu + ((u >> 16) & 1u)) >> 16);   // RNE
}
__device__ __forceinline__ float bf2f(unsigned short h) {
  union { unsigned int u; float f; } c; c.u = ((unsigned int)h) << 16;
  return c.f;
}

// ----------------------------- GCN via MFMA (unchanged, verified R12/R13) -------------------------------
template<int Fin, int Fout, bool RELU>
__device__ __forceinline__ void gcn_layer_mfma(
    const unsigned short* __restrict__ WT, const float* __restrict__ bias,
    unsigned short* hbuf, unsigned short* stT, const unsigned short* Ab,
    unsigned short* __restrict__ outG, int g, int tid)
{
  const int lane = tid & 63, w = tid >> 6;
  const int c = lane & 15, q = lane >> 4;
  constexpr int NT = Fout / 16;
  constexpr int KS = Fin / 32;

  // GEMM1: st = h @ W -> stT[fout][node]
#pragma unroll
  for (int nt = 0; nt < NT; ++nt) {
    f32x4 acc = {0.f, 0.f, 0.f, 0.f};
#pragma unroll
    for (int ks = 0; ks < KS; ++ks) {
      s16x8 a = *reinterpret_cast<const s16x8*>(hbuf + (w * 16 + c) * 72 + ks * 32 + q * 8);
      s16x8 b = *reinterpret_cast<const s16x8*>(WT + (nt * 16 + c) * Fin + ks * 32 + q * 8);
      acc = __builtin_amdgcn_mfma_f32_16x16x32_bf16(a, b, acc, 0, 0, 0);
    }
    unsigned int w0 = (unsigned int)f2bf(acc[0]) | ((unsigned int)f2bf(acc[1]) << 16);
    unsigned int w1 = (unsigned int)f2bf(acc[2]) | ((unsigned int)f2bf(acc[3]) << 16);
    *reinterpret_cast<uint2*>(stT + (nt * 16 + c) * 72 + w * 16 + q * 4) = make_uint2(w0, w1);
  }
  __syncthreads();

  // GEMM2: out[f][dst] = sum_src st[src][f] * A[dst][src]
#pragma unroll
  for (int mt = 0; mt < NT; ++mt) {
    f32x4 acc = {0.f, 0.f, 0.f, 0.f};
#pragma unroll
    for (int ks = 0; ks < 2; ++ks) {
      s16x8 a = *reinterpret_cast<const s16x8*>(stT + (mt * 16 + c) * 72 + ks * 32 + q * 8);
      s16x8 b = *reinterpret_cast<const s16x8*>(Ab + (w * 16 + c) * 72 + ks * 32 + q * 8);
      acc = __builtin_amdgcn_mfma_f32_16x16x32_bf16(a, b, acc, 0, 0, 0);
    }
    const int node = w * 16 + c, f0 = mt * 16 + q * 4;
    unsigned short pk[4], pr[4];
#pragma unroll
    for (int r = 0; r < 4; ++r) {
      float v = acc[r] + bias[f0 + r];
      pk[r] = f2bf(v);
      pr[r] = f2bf(fmaxf(v, 0.f));
    }
    *reinterpret_cast<uint2*>(outG + (size_t)(g * MM + node) * Fout + f0) =
        make_uint2((unsigned int)pk[0] | ((unsigned int)pk[1] << 16),
                   (unsigned int)pk[2] | ((unsigned int)pk[3] << 16));
    if (RELU)
      *reinterpret_cast<uint2*>(hbuf + node * 72 + f0) =
          make_uint2((unsigned int)pr[0] | ((unsigned int)pr[1] << 16),
                     (unsigned int)pr[2] | ((unsigned int)pr[3] << 16));
  }
  __syncthreads();
}

__global__ __launch_bounds__(256) void gcn_kernel(
    const float* __restrict__ xq, const float* __restrict__ xc,
    const int* __restrict__ srcq, const int* __restrict__ dstq,
    const int* __restrict__ srcc, const int* __restrict__ dstc,
    const unsigned short* __restrict__ WgT,
    const float* __restrict__ bg0, const float* __restrict__ bg1, const float* __restrict__ bg2,
    unsigned short* __restrict__ qf0, unsigned short* __restrict__ qf1,
    unsigned short* __restrict__ qf2, unsigned short* __restrict__ cf0,
    unsigned short* __restrict__ cf1, unsigned short* __restrict__ cf2)
{
  __shared__ __align__(16) unsigned short smem[13824];  // hbuf|stT|Ab, each [64][72]
  __shared__ float sDinv[MM];
  __shared__ int sDeg[MM];
  unsigned short* hbuf = smem;
  unsigned short* stT  = smem + 4608;
  unsigned short* Ab   = smem + 9216;
  float* sAf = reinterpret_cast<float*>(smem);   // [64][68] fp32, aliases hbuf+stT (build phase only)

  const int g = blockIdx.x;
  const int which = blockIdx.y;
  const float* x = which ? xc : xq;
  const int* src = which ? srcc : srcq;
  const int* dst = which ? dstc : dstq;
  unsigned short* f0p = which ? cf0 : qf0;
  unsigned short* f1p = which ? cf1 : qf1;
  unsigned short* f2p = which ? cf2 : qf2;
  const int tid = threadIdx.x;

  for (int i = tid; i < 64 * 68; i += 256) sAf[i] = 0.f;
  if (tid < MM) sDeg[tid] = 1;
  __syncthreads();
  for (int e = tid; e < EPGc; e += 256)
    atomicAdd(&sDeg[dst[g * EPGc + e] - g * MM], 1);
  __syncthreads();
  if (tid < MM) sDinv[tid] = rsqrtf((float)sDeg[tid]);
  __syncthreads();
  for (int e = tid; e < EPGc; e += 256) {
    int s = src[g * EPGc + e] - g * MM;
    int d = dst[g * EPGc + e] - g * MM;
    atomicAdd(&sAf[d * 68 + s], sDinv[s] * sDinv[d]);
  }
  if (tid < MM) atomicAdd(&sAf[tid * 68 + tid], sDinv[tid] * sDinv[tid]);
  __syncthreads();
  for (int i = tid; i < 4096; i += 256) {
    int r = i >> 6, s = i & 63;
    Ab[r * 72 + s] = f2bf(sAf[r * 68 + s]);
  }
  __syncthreads();
  {
    const float* xs = x + (size_t)g * 2048 + tid * 8;
    float4 v0 = *reinterpret_cast<const float4*>(xs);
    float4 v1 = *reinterpret_cast<const float4*>(xs + 4);
    s16x8 p;
    p[0] = (short)f2bf(v0.x); p[1] = (short)f2bf(v0.y); p[2] = (short)f2bf(v0.z); p[3] = (short)f2bf(v0.w);
    p[4] = (short)f2bf(v1.x); p[5] = (short)f2bf(v1.y); p[6] = (short)f2bf(v1.z); p[7] = (short)f2bf(v1.w);
    int node = tid >> 2, k = (tid & 3) * 8;
    *reinterpret_cast<s16x8*>(hbuf + node * 72 + k) = p;
  }
  __syncthreads();

  gcn_layer_mfma<32, 64, true >(WgT,        bg0, hbuf, stT, Ab, f0p, g, tid);
  gcn_layer_mfma<64, 32, true >(WgT + 2048, bg1, hbuf, stT, Ab, f1p, g, tid);
  gcn_layer_mfma<32, 16, false>(WgT + 4096, bg2, hbuf, stT, Ab, f2p, g, tid);
}

// ----------------------------- merged prep (unchanged, verified R13) -----------------------------------
__global__ __launch_bounds__(256) void prep_misc(
    const float* __restrict__ cw1, const float* __restrict__ cw0,
    const float* __restrict__ Wg0, const float* __restrict__ Wg1, const float* __restrict__ Wg2,
    const float* __restrict__ Wl0,
    unsigned short* __restrict__ packA, unsigned short* __restrict__ packW1,
    unsigned short* __restrict__ WgT, unsigned short* __restrict__ WT)
{
  __shared__ float tile[64][65];
  const int b = blockIdx.x, t = threadIdx.x;
  if (b < 42) {                        // pack_w: conv2 A-frag
    int i = b * 256 + t;
    if (i < 10752) {
      int j = i & 7, l = (i >> 3) & 63, g = (i >> 9) % 7, lvl = i / 3584;
      int oc = l & 15, sg = l >> 4;
      int s = g * 4 + sg;
      float v = 0.f;
      if (s < 25) v = cw1[((size_t)(lvl * 16 + oc) * 8 + j) * 25 + s];
      packA[i] = f2bf(v);
    }
    return;
  }
  if (b < 54) {                        // pack_w1: conv1 COL-SHIFT A-frag (R11-verified mapping)
    int i = (b - 42) * 256 + t;
    if (i < 3072) {
      int j = i & 7, lane = (i >> 3) & 63, gg = (i >> 9) & 1, lvl = i >> 10;
      int m = lane & 15, q = lane >> 4;
      int u = gg * 4 + q;
      int oc = m & 7;
      float v = 0.f;
      if (u < 5) {
        if (m < 8) { if (j < 5) v = cw0[((size_t)(lvl * 8 + oc)) * 25 + u * 5 + j]; }
        else       { if (j >= 1 && j <= 5) v = cw0[((size_t)(lvl * 8 + oc)) * 25 + u * 5 + (j - 1)]; }
      }
      packW1[i] = f2bf(v);
    }
    return;
  }
  if (b < 72) {                        // pack WgT
    int i = (b - 54) * 256 + t;
    if (i < 2048) {
      int n = i >> 5, k = i & 31;
      WgT[i] = f2bf(Wg0[k * 64 + n]);
    } else if (i < 4096) {
      int j = i - 2048, n = j >> 6, k = j & 63;
      WgT[i] = f2bf(Wg1[k * 32 + n]);
    } else if (i < 4608) {
      int j = i - 4096, n = j >> 5, k = j & 31;
      WgT[i] = f2bf(Wg2[k * 16 + n]);
    }
    return;
  }
  {                                    // pack_wl0: Wl0 -> bf16 WT[n][k]
    int bb = b - 72;                   // 768 blocks: 192 kb x 4 nb
    const int kb = (bb % 192) * 64;
    const int nb = (bb / 192) * 64;
#pragma unroll
    for (int i = 0; i < 16; ++i) {
      int idx = i * 256 + t, kk = idx >> 6, nn = idx & 63;
      tile[kk][nn] = Wl0[(size_t)(kb + kk) * 256 + nb + nn];
    }
    __syncthreads();
#pragma unroll
    for (int i = 0; i < 16; ++i) {
      int idx = i * 256 + t, nn = idx >> 6, kk = idx & 63;
      WT[(size_t)(nb + nn) * 12288 + kb + kk] = f2bf(tile[kk][nn]);
    }
  }
}

// ----------------------------- fused sim + conv1 + conv2 ------------------------------------------------
// sim: MFMA operands straight from global (bf16, k-contiguous). D -> TWO LDS copies:
//   cp0[row][x]  (u16, stride 80)  and  cpS: cpS u16 index X == cp0 u16 X+2 (dword-shifted copy).
// conv1: lane's window [2P, 2P+8) u16 = 2 ALIGNED ds_read_b64 from cp0@dword P (P even)
//   or cpS@dword P-1 (P odd). A-operand identical to R11-verified layout.
template<int F>
__device__ __forceinline__ void sim_mfma(const unsigned short* __restrict__ qf,
    const unsigned short* __restrict__ cf, unsigned short* cp0, unsigned short* cpS,
    int g, int tid)
{
  // zero BOTH copies: 2*5760 u16 = 5760 u32 contiguous (cpS directly follows cp0)
  {
    unsigned int* z = reinterpret_cast<unsigned int*>(cp0);
    for (int i = tid; i < 5760; i += 256) z[i] = 0u;
  }

  const int lane = tid & 63, wave = tid >> 6;
  const int c = lane & 15, q = lane >> 4;
  constexpr int NK = (F == 64) ? 2 : 1;
  const unsigned short* qg = qf + (size_t)g * 64 * F;
  const unsigned short* cg = cf + (size_t)g * 64 * F;
  const bool zlane = (F == 16) && (q >= 2);   // k>=16 slots are zero for F=16
  const s16x8 zz8 = {0, 0, 0, 0, 0, 0, 0, 0};

  f32x4 acc[4];
#pragma unroll
  for (int nt = 0; nt < 4; ++nt) acc[nt] = (f32x4){0.f, 0.f, 0.f, 0.f};
#pragma unroll
  for (int ks = 0; ks < NK; ++ks) {
    s16x8 af = zlane ? zz8
        : *reinterpret_cast<const s16x8*>(qg + (wave * 16 + c) * F + ks * 32 + q * 8);
#pragma unroll
    for (int nt = 0; nt < 4; ++nt) {
      s16x8 bf = zlane ? zz8
          : *reinterpret_cast<const s16x8*>(cg + (nt * 16 + c) * F + ks * 32 + q * 8);
      acc[nt] = __builtin_amdgcn_mfma_f32_16x16x32_bf16(af, bf, acc[nt], 0, 0, 0);
    }
  }
  __syncthreads();   // zeroing complete before D-writes

  // D: image row i = wave*16 + q*4 + r, image col n = nt*16 + c
#pragma unroll
  for (int nt = 0; nt < 4; ++nt)
#pragma unroll
    for (int r = 0; r < 4; ++r) {
      unsigned short bv = f2bf(acc[nt][r]);
      int off = (wave * 16 + q * 4 + r + 2) * 80 + nt * 16 + c + 2;
      cp0[off] = bv;
      cpS[off - 2] = bv;      // cpS u16 X == cp0 u16 X+2
    }
  __syncthreads();
}

__device__ __forceinline__ void conv1_mfma(const unsigned short* cp0, const unsigned short* cpS,
    unsigned short* p1u, const unsigned short* __restrict__ packW1,
    const float* __restrict__ cb0, int lvl, int tid)
{
  const int lane = tid & 63, wave = tid >> 6;
  const int c = lane & 15, q = lane >> 4;

  // zero p1ci halo frame (272 cells, strided)
  for (int h = tid; h < 272; h += 256) {
    int r, cc;
    if (h < 72)       { r = h / 36;             cc = h % 36; }
    else if (h < 144) { r = 34 + (h - 72) / 36; cc = (h - 72) % 36; }
    else { int z = h - 144; r = 2 + (z >> 2); int wq = z & 3; cc = (wq < 2) ? wq : 32 + wq; }
    s16x8 zz = {0, 0, 0, 0, 0, 0, 0, 0};
    *reinterpret_cast<s16x8*>(p1u + (r * 36 + cc) * 8) = zz;
  }

  s16x8 aw0 = *reinterpret_cast<const s16x8*>(packW1 + ((size_t)(lvl * 2 + 0) * 64 + lane) * 8);
  s16x8 aw1 = *reinterpret_cast<const s16x8*>(packW1 + ((size_t)(lvl * 2 + 1) * 64 + lane) * 8);
  float bias[4];
#pragma unroll
  for (int r = 0; r < 4; ++r) bias[r] = cb0[lvl * 8 + (q & 1) * 4 + r];

  const int p = c & 1;                 // parity of this lane's pooled col
  const unsigned int* bsel = reinterpret_cast<const unsigned int*>(p ? cpS : cp0);

  for (int pp = 0; pp < 8; ++pp) {
    const int Y = wave * 8 + pp;          // pooled row
    const int y0 = 2 * Y;
#pragma unroll
    for (int Xi = 0; Xi < 2; ++Xi) {
      const int P = Xi * 16 + c;          // pooled col; window u16 [2P, 2P+8)
      const int dbase = P - p;            // EVEN dword base in selected copy
      const int r00 = (y0 + q) * 40 + dbase;        // acc0 (row y0),   gg=0: u = q
      const int r01 = (y0 + 4 + q) * 40 + dbase;    // acc0,            gg=1: u = 4+q
      const int r10 = (y0 + 1 + q) * 40 + dbase;    // acc1 (row y0+1), gg=0
      const int r11 = (y0 + 5 + q) * 40 + dbase;    // acc1,            gg=1
      union { uint2 d[2]; s16x8 v; } f00, f01, f10, f11;
      f00.d[0] = *reinterpret_cast<const uint2*>(bsel + r00);
      f00.d[1] = *reinterpret_cast<const uint2*>(bsel + r00 + 2);
      f01.d[0] = *reinterpret_cast<const uint2*>(bsel + r01);
      f01.d[1] = *reinterpret_cast<const uint2*>(bsel + r01 + 2);
      f10.d[0] = *reinterpret_cast<const uint2*>(bsel + r10);
      f10.d[1] = *reinterpret_cast<const uint2*>(bsel + r10 + 2);
      f11.d[0] = *reinterpret_cast<const uint2*>(bsel + r11);
      f11.d[1] = *reinterpret_cast<const uint2*>(bsel + r11 + 2);
      f32x4 a0 = {0.f, 0.f, 0.f, 0.f}, a1 = {0.f, 0.f, 0.f, 0.f};
      a0 = __builtin_amdgcn_mfma_f32_16x16x32_bf16(aw0, f00.v, a0, 0, 0, 0);
      a0 = __builtin_amdgcn_mfma_f32_16x16x32_bf16(aw1, f01.v, a0, 0, 0, 0);
      a1 = __builtin_amdgcn_mfma_f32_16x16x32_bf16(aw0, f10.v, a1, 0, 0, 0);
      a1 = __builtin_amdgcn_mfma_f32_16x16x32_bf16(aw1, f11.v, a1, 0, 0, 0);
      // pool: ALL lanes compute (convergent shuffles); stores predicated
      float pv[4];
#pragma unroll
      for (int r = 0; r < 4; ++r) {
        float vm = fmaxf(a0[r], a1[r]);             // vertical pool (register)
        float hp = fmaxf(vm, __shfl_xor(vm, 32));   // horizontal pool (x <-> x+1)
        pv[r] = fmaxf(hp + bias[r], 0.f);
      }
      if (q < 2) {
        unsigned short pk[4];
#pragma unroll
        for (int r = 0; r < 4; ++r) pk[r] = f2bf(pv[r]);
        unsigned int w0 = (unsigned int)pk[0] | ((unsigned int)pk[1] << 16);
        unsigned int w1 = (unsigned int)pk[2] | ((unsigned int)pk[3] << 16);
        *reinterpret_cast<uint2*>(p1u + (((Y + 2) * 36) + (P + 2)) * 8 + q * 4) =
            make_uint2(w0, w1);
      }
    }
  }
  __syncthreads();
}

__global__ __launch_bounds__(256) void simconv_kernel(
    const unsigned short* __restrict__ qf0, const unsigned short* __restrict__ qf1,
    const unsigned short* __restrict__ qf2, const unsigned short* __restrict__ cf0,
    const unsigned short* __restrict__ cf1, const unsigned short* __restrict__ cf2,
    const float* __restrict__ cb0, const float* __restrict__ cb1,
    const unsigned short* __restrict__ packA, const unsigned short* __restrict__ packW1,
    unsigned short* __restrict__ hcat)
{
  __shared__ __align__(16) unsigned short smem[21888];   // 43776 B -> 3 blocks/CU
  // p1u [0,10368) conv1->conv2 ; cp0 [10368,16128) ; cpS [16128,21888)  (cpS = cp0 shifted 1 dword)
  unsigned short* p1u = smem;
  unsigned short* cp0 = smem + 10368;
  unsigned short* cpS = smem + 16128;

  const int g = blockIdx.x, lvl = blockIdx.y, tid = threadIdx.x;

  if (lvl == 0)      sim_mfma<64>(qf0, cf0, cp0, cpS, g, tid);
  else if (lvl == 1) sim_mfma<32>(qf1, cf1, cp0, cpS, g, tid);
  else               sim_mfma<16>(qf2, cf2, cp0, cpS, g, tid);

  conv1_mfma(cp0, cpS, p1u, packW1, cb0, lvl, tid);

  // ---- conv2 via MFMA + in-register 2x2 pool -> bf16 hcat (unchanged, verified) ----
  {
    const int lane = tid & 63, wave = tid >> 6;
    const int col = lane & 15, q = lane >> 4;

    s16x8 afr[7];
#pragma unroll
    for (int gg = 0; gg < 7; ++gg)
      afr[gg] = *reinterpret_cast<const s16x8*>(packA + ((size_t)(lvl * 7 + gg) * 64 + lane) * 8);

    int off[7];
#pragma unroll
    for (int gg = 0; gg < 7; ++gg) {
      int s = gg * 4 + q; if (s > 24) s = 24;
      off[gg] = (s / 5) * 288 + (s % 5) * 8;
    }
    float bias2[4];
#pragma unroll
    for (int r = 0; r < 4; ++r) bias2[r] = cb1[lvl * 16 + q * 4 + r];

    for (int pq = 0; pq < 4; ++pq) {
      const int py = wave * 4 + pq;
#pragma unroll
      for (int h = 0; h < 2; ++h) {
        const int base0 = (2 * py) * 288 + h * 128 + col * 8;
        const int base1 = base0 + 288;
        f32x4 a0 = {0.f, 0.f, 0.f, 0.f}, a1 = {0.f, 0.f, 0.f, 0.f};
#pragma unroll
        for (int gg = 0; gg < 7; ++gg) {
          s16x8 b0 = *reinterpret_cast<const s16x8*>(p1u + base0 + off[gg]);
          a0 = __builtin_amdgcn_mfma_f32_16x16x32_bf16(afr[gg], b0, a0, 0, 0, 0);
          s16x8 b1 = *reinterpret_cast<const s16x8*>(p1u + base1 + off[gg]);
          a1 = __builtin_amdgcn_mfma_f32_16x16x32_bf16(afr[gg], b1, a1, 0, 0, 0);
        }
        float val[4];
#pragma unroll
        for (int r = 0; r < 4; ++r) {
          float vm = fmaxf(a0[r], a1[r]);
          float hp = fmaxf(vm, __shfl_xor(vm, 1));
          val[r] = fmaxf(hp + bias2[r], 0.f);
        }
        if ((col & 1) == 0) {
          int px = h * 8 + (col >> 1);
#pragma unroll
          for (int r = 0; r < 4; ++r)
            hcat[((size_t)g * 48 + lvl * 16 + q * 4 + r) * 256 + py * 16 + px] = f2bf(val[r]);
        }
      }
    }
  }
}

// ----------------------------- linear 0 via MFMA: non-atomic split-K partials (unchanged) ---------------
__global__ __launch_bounds__(256) void lin0_kernel(
    const unsigned short* __restrict__ A, const unsigned short* __restrict__ WT,
    float* __restrict__ part)
{
  __shared__ __align__(16) unsigned short sAb[64 * 72];
  __shared__ __align__(16) unsigned short sBb[64 * 72];
  const int rb = blockIdx.x * 64;
  const int cb = blockIdx.y * 64;
  const int k0 = blockIdx.z * 768;
  const int tid = threadIdx.x;
  const int lane = tid & 63, wave = tid >> 6;
  const int wm = wave >> 1, wn = wave & 1;
  const int c = lane & 15, kg = lane >> 4;
  const int srow = tid >> 2;
  const int skq  = (tid & 3) * 16;

  f32x4 acc[2][2];
#pragma unroll
  for (int i = 0; i < 2; ++i)
#pragma unroll
    for (int j = 0; j < 2; ++j) acc[i][j] = (f32x4){0.f, 0.f, 0.f, 0.f};

  for (int kt = 0; kt < 768; kt += 64) {
    {
      const unsigned short* src = A + (size_t)(rb + srow) * 12288 + k0 + kt + skq;
      s16x8 a0 = *reinterpret_cast<const s16x8*>(src);
      s16x8 a1 = *reinterpret_cast<const s16x8*>(src + 8);
      *reinterpret_cast<s16x8*>(sAb + srow * 72 + skq)     = a0;
      *reinterpret_cast<s16x8*>(sAb + srow * 72 + skq + 8) = a1;
    }
    {
      const unsigned short* src = WT + (size_t)(cb + srow) * 12288 + k0 + kt + skq;
      s16x8 w0 = *reinterpret_cast<const s16x8*>(src);
      s16x8 w1 = *reinterpret_cast<const s16x8*>(src + 8);
      *reinterpret_cast<s16x8*>(sBb + srow * 72 + skq)     = w0;
      *reinterpret_cast<s16x8*>(sBb + srow * 72 + skq + 8) = w1;
    }
    __syncthreads();

#pragma unroll
    for (int kb = 0; kb < 64; kb += 32) {
      s16x8 a0 = *reinterpret_cast<const s16x8*>(sAb + (wm * 32 +  0 + c) * 72 + kb + kg * 8);
      s16x8 a1 = *reinterpret_cast<const s16x8*>(sAb + (wm * 32 + 16 + c) * 72 + kb + kg * 8);
      s16x8 b0 = *reinterpret_cast<const s16x8*>(sBb + (wn * 32 +  0 + c) * 72 + kb + kg * 8);
      s16x8 b1 = *reinterpret_cast<const s16x8*>(sBb + (wn * 32 + 16 + c) * 72 + kb + kg * 8);
      acc[0][0] = __builtin_amdgcn_mfma_f32_16x16x32_bf16(a0, b0, acc[0][0], 0, 0, 0);
      acc[0][1] = __builtin_amdgcn_mfma_f32_16x16x32_bf16(a0, b1, acc[0][1], 0, 0, 0);
      acc[1][0] = __builtin_amdgcn_mfma_f32_16x16x32_bf16(a1, b0, acc[1][0], 0, 0, 0);
      acc[1][1] = __builtin_amdgcn_mfma_f32_16x16x32_bf16(a1, b1, acc[1][1], 0, 0, 0);
    }
    __syncthreads();
  }

  float* dstp = part + (size_t)blockIdx.z * 512 * 256;
#pragma unroll
  for (int i = 0; i < 2; ++i)
#pragma unroll
    for (int j = 0; j < 2; ++j)
#pragma unroll
      for (int r = 0; r < 4; ++r) {
        int row = rb + wm * 32 + i * 16 + kg * 4 + r;
        int col = cb + wn * 32 + j * 16 + c;
        dstp[(size_t)row * 256 + col] = acc[i][j][r];
      }
}

// ----------------------------- head: 16-way partial reduce + bias + relu -> lin1 -> score ---------------
__global__ __launch_bounds__(64) void head_kernel(
    const float* __restrict__ part, const float* __restrict__ bl0,
    const float* __restrict__ Wl1, const float* __restrict__ bl1,
    const float* __restrict__ Wsc, const float* __restrict__ bsc, float* __restrict__ out)
{
  __shared__ float sr[256];
  const int b = blockIdx.x, j = threadIdx.x;
  {
    float4 s = *reinterpret_cast<const float4*>(bl0 + j * 4);
#pragma unroll
    for (int z = 0; z < 16; ++z) {
      float4 p = *reinterpret_cast<const float4*>(part + ((size_t)z * 512 + b) * 256 + j * 4);
      s.x += p.x; s.y += p.y; s.z += p.z; s.w += p.w;
    }
    sr[j * 4 + 0] = fmaxf(s.x, 0.f);
    sr[j * 4 + 1] = fmaxf(s.y, 0.f);
    sr[j * 4 + 2] = fmaxf(s.z, 0.f);
    sr[j * 4 + 3] = fmaxf(s.w, 0.f);
  }
  __syncthreads();
  float acc = bl1[j];
  for (int k = 0; k < 256; ++k) acc = fmaf(sr[k], Wl1[k * 64 + j], acc);
  float v = fmaxf(acc, 0.f) * Wsc[j];
#pragma unroll
  for (int off = 32; off > 0; off >>= 1) v += __shfl_down(v, off);
  if (j == 0) out[b] = 1.f / (1.f + expf(-(v + bsc[0])));
}

// ----------------------------- launch -----------------------------
extern "C" void kernel_launch(void* const* d_in, const int* in_sizes, int n_in,
                              void* d_out, int out_size, void* d_ws, size_t ws_size,
                              hipStream_t stream)
{
  (void)in_sizes; (void)n_in; (void)out_size; (void)ws_size;
  const float* x_q = (const float*)d_in[0];
  const float* x_c = (const float*)d_in[1];
  const int*   src_q = (const int*)d_in[2];
  const int*   dst_q = (const int*)d_in[3];
  const int*   src_c = (const int*)d_in[4];
  const int*   dst_c = (const int*)d_in[5];
  const float* Wg0 = (const float*)d_in[6];
  const float* bg0 = (const float*)d_in[7];
  const float* Wg1 = (const float*)d_in[8];
  const float* bg1 = (const float*)d_in[9];
  const float* Wg2 = (const float*)d_in[10];
  const float* bg2 = (const float*)d_in[11];
  const float* cw0 = (const float*)d_in[12];
  const float* cb0 = (const float*)d_in[13];
  const float* cw1 = (const float*)d_in[14];
  const float* cb1 = (const float*)d_in[15];
  const float* Wl0 = (const float*)d_in[16];
  const float* bl0 = (const float*)d_in[17];
  const float* Wl1 = (const float*)d_in[18];
  const float* bl1 = (const float*)d_in[19];
  const float* Wsc = (const float*)d_in[20];
  const float* bsc = (const float*)d_in[21];
  float* out = (float*)d_out;

  // workspace carve (float-granular; all u16 regions even-sized)
  float* ws = (float*)d_ws;
  unsigned short* qf0 = (unsigned short*)ws; ws += (size_t)NB * MM * 64 / 2;
  unsigned short* qf1 = (unsigned short*)ws; ws += (size_t)NB * MM * 32 / 2;
  unsigned short* qf2 = (unsigned short*)ws; ws += (size_t)NB * MM * 16 / 2;
  unsigned short* cf0 = (unsigned short*)ws; ws += (size_t)NB * MM * 64 / 2;
  unsigned short* cf1 = (unsigned short*)ws; ws += (size_t)NB * MM * 32 / 2;
  unsigned short* cf2 = (unsigned short*)ws; ws += (size_t)NB * MM * 16 / 2;
  unsigned short* hcat = (unsigned short*)ws; ws += (size_t)NB * 48 * 256 / 2;
  float* part = ws; ws += (size_t)16 * 512 * 256;              // 8.4 MB split-K partials
  unsigned short* packA  = (unsigned short*)ws; ws += 5376;    // 10752 bf16
  unsigned short* packW1 = (unsigned short*)ws; ws += 1536;    // 3072 bf16
  unsigned short* WgT    = (unsigned short*)ws; ws += 2304;    // 4608 bf16
  unsigned short* WT = (unsigned short*)ws; ws += (size_t)256 * 12288 / 2;

  prep_misc<<<840, 256, 0, stream>>>(cw1, cw0, Wg0, Wg1, Wg2, Wl0,
                                     packA, packW1, WgT, WT);

  gcn_kernel<<<dim3(NB, 2), 256, 0, stream>>>(x_q, x_c, src_q, dst_q, src_c, dst_c,
      WgT, bg0, bg1, bg2, qf0, qf1, qf2, cf0, cf1, cf2);

  simconv_kernel<<<dim3(NB, 3), 256, 0, stream>>>(qf0, qf1, qf2, cf0, cf1, cf2,
      cb0, cb1, packA, packW1, hcat);

  lin0_kernel<<<dim3(8, 4, 16), 256, 0, stream>>>(hcat, WT, part);
  head_kernel<<<NB, 64, 0, stream>>>(part, bl0, Wl1, bl1, Wsc, bsc, out);
}

// Round 15
// 79.660 us; speedup vs baseline: 1.0230x; 1.0230x over previous
//
#include <hip/hip_runtime.h>
#include <math.h>

#define NB 512      // graph pairs
#define MM 64       // nodes per graph
#define EPGc 512    // edges per graph

typedef __attribute__((ext_vector_type(8))) short s16x8;
typedef __attribute__((ext_vector_type(4))) float f32x4;

__device__ __forceinline__ unsigned short f2bf(float f) {
  union { float f; unsigned int u; } c; c.f = f;
  unsigned int u = c.u;
  return (unsigned short)((u + 0x7FFFu + ((u >> 16) & 1u)) >> 16);   // RNE
}
__device__ __forceinline__ float bf2f(unsigned short h) {
  union { unsigned int u; float f; } c; c.u = ((unsigned int)h) << 16;
  return c.f;
}

// ----------------------------- GCN via MFMA (unchanged, verified R12/R13) -------------------------------
template<int Fin, int Fout, bool RELU>
__device__ __forceinline__ void gcn_layer_mfma(
    const unsigned short* __restrict__ WT, const float* __restrict__ bias,
    unsigned short* hbuf, unsigned short* stT, const unsigned short* Ab,
    unsigned short* __restrict__ outG, int g, int tid)
{
  const int lane = tid & 63, w = tid >> 6;
  const int c = lane & 15, q = lane >> 4;
  constexpr int NT = Fout / 16;
  constexpr int KS = Fin / 32;

  // GEMM1: st = h @ W -> stT[fout][node]
#pragma unroll
  for (int nt = 0; nt < NT; ++nt) {
    f32x4 acc = {0.f, 0.f, 0.f, 0.f};
#pragma unroll
    for (int ks = 0; ks < KS; ++ks) {
      s16x8 a = *reinterpret_cast<const s16x8*>(hbuf + (w * 16 + c) * 72 + ks * 32 + q * 8);
      s16x8 b = *reinterpret_cast<const s16x8*>(WT + (nt * 16 + c) * Fin + ks * 32 + q * 8);
      acc = __builtin_amdgcn_mfma_f32_16x16x32_bf16(a, b, acc, 0, 0, 0);
    }
    unsigned int w0 = (unsigned int)f2bf(acc[0]) | ((unsigned int)f2bf(acc[1]) << 16);
    unsigned int w1 = (unsigned int)f2bf(acc[2]) | ((unsigned int)f2bf(acc[3]) << 16);
    *reinterpret_cast<uint2*>(stT + (nt * 16 + c) * 72 + w * 16 + q * 4) = make_uint2(w0, w1);
  }
  __syncthreads();

  // GEMM2: out[f][dst] = sum_src st[src][f] * A[dst][src]
#pragma unroll
  for (int mt = 0; mt < NT; ++mt) {
    f32x4 acc = {0.f, 0.f, 0.f, 0.f};
#pragma unroll
    for (int ks = 0; ks < 2; ++ks) {
      s16x8 a = *reinterpret_cast<const s16x8*>(stT + (mt * 16 + c) * 72 + ks * 32 + q * 8);
      s16x8 b = *reinterpret_cast<const s16x8*>(Ab + (w * 16 + c) * 72 + ks * 32 + q * 8);
      acc = __builtin_amdgcn_mfma_f32_16x16x32_bf16(a, b, acc, 0, 0, 0);
    }
    const int node = w * 16 + c, f0 = mt * 16 + q * 4;
    unsigned short pk[4], pr[4];
#pragma unroll
    for (int r = 0; r < 4; ++r) {
      float v = acc[r] + bias[f0 + r];
      pk[r] = f2bf(v);
      pr[r] = f2bf(fmaxf(v, 0.f));
    }
    *reinterpret_cast<uint2*>(outG + (size_t)(g * MM + node) * Fout + f0) =
        make_uint2((unsigned int)pk[0] | ((unsigned int)pk[1] << 16),
                   (unsigned int)pk[2] | ((unsigned int)pk[3] << 16));
    if (RELU)
      *reinterpret_cast<uint2*>(hbuf + node * 72 + f0) =
          make_uint2((unsigned int)pr[0] | ((unsigned int)pr[1] << 16),
                     (unsigned int)pr[2] | ((unsigned int)pr[3] << 16));
  }
  __syncthreads();
}

__global__ __launch_bounds__(256) void gcn_kernel(
    const float* __restrict__ xq, const float* __restrict__ xc,
    const int* __restrict__ srcq, const int* __restrict__ dstq,
    const int* __restrict__ srcc, const int* __restrict__ dstc,
    const unsigned short* __restrict__ WgT,
    const float* __restrict__ bg0, const float* __restrict__ bg1, const float* __restrict__ bg2,
    unsigned short* __restrict__ qf0, unsigned short* __restrict__ qf1,
    unsigned short* __restrict__ qf2, unsigned short* __restrict__ cf0,
    unsigned short* __restrict__ cf1, unsigned short* __restrict__ cf2)
{
  __shared__ __align__(16) unsigned short smem[13824];  // hbuf|stT|Ab, each [64][72]
  __shared__ float sDinv[MM];
  __shared__ int sDeg[MM];
  unsigned short* hbuf = smem;
  unsigned short* stT  = smem + 4608;
  unsigned short* Ab   = smem + 9216;
  float* sAf = reinterpret_cast<float*>(smem);   // [64][68] fp32, aliases hbuf+stT (build phase only)

  const int g = blockIdx.x;
  const int which = blockIdx.y;
  const float* x = which ? xc : xq;
  const int* src = which ? srcc : srcq;
  const int* dst = which ? dstc : dstq;
  unsigned short* f0p = which ? cf0 : qf0;
  unsigned short* f1p = which ? cf1 : qf1;
  unsigned short* f2p = which ? cf2 : qf2;
  const int tid = threadIdx.x;

  for (int i = tid; i < 64 * 68; i += 256) sAf[i] = 0.f;
  if (tid < MM) sDeg[tid] = 1;
  __syncthreads();
  for (int e = tid; e < EPGc; e += 256)
    atomicAdd(&sDeg[dst[g * EPGc + e] - g * MM], 1);
  __syncthreads();
  if (tid < MM) sDinv[tid] = rsqrtf((float)sDeg[tid]);
  __syncthreads();
  for (int e = tid; e < EPGc; e += 256) {
    int s = src[g * EPGc + e] - g * MM;
    int d = dst[g * EPGc + e] - g * MM;
    atomicAdd(&sAf[d * 68 + s], sDinv[s] * sDinv[d]);
  }
  if (tid < MM) atomicAdd(&sAf[tid * 68 + tid], sDinv[tid] * sDinv[tid]);
  __syncthreads();
  for (int i = tid; i < 4096; i += 256) {
    int r = i >> 6, s = i & 63;
    Ab[r * 72 + s] = f2bf(sAf[r * 68 + s]);
  }
  __syncthreads();
  {
    const float* xs = x + (size_t)g * 2048 + tid * 8;
    float4 v0 = *reinterpret_cast<const float4*>(xs);
    float4 v1 = *reinterpret_cast<const float4*>(xs + 4);
    s16x8 p;
    p[0] = (short)f2bf(v0.x); p[1] = (short)f2bf(v0.y); p[2] = (short)f2bf(v0.z); p[3] = (short)f2bf(v0.w);
    p[4] = (short)f2bf(v1.x); p[5] = (short)f2bf(v1.y); p[6] = (short)f2bf(v1.z); p[7] = (short)f2bf(v1.w);
    int node = tid >> 2, k = (tid & 3) * 8;
    *reinterpret_cast<s16x8*>(hbuf + node * 72 + k) = p;
  }
  __syncthreads();

  gcn_layer_mfma<32, 64, true >(WgT,        bg0, hbuf, stT, Ab, f0p, g, tid);
  gcn_layer_mfma<64, 32, true >(WgT + 2048, bg1, hbuf, stT, Ab, f1p, g, tid);
  gcn_layer_mfma<32, 16, false>(WgT + 4096, bg2, hbuf, stT, Ab, f2p, g, tid);
}

// ----------------------------- merged prep (unchanged, verified R13) -----------------------------------
__global__ __launch_bounds__(256) void prep_misc(
    const float* __restrict__ cw1, const float* __restrict__ cw0,
    const float* __restrict__ Wg0, const float* __restrict__ Wg1, const float* __restrict__ Wg2,
    const float* __restrict__ Wl0,
    unsigned short* __restrict__ packA, unsigned short* __restrict__ packW1,
    unsigned short* __restrict__ WgT, unsigned short* __restrict__ WT)
{
  __shared__ float tile[64][65];
  const int b = blockIdx.x, t = threadIdx.x;
  if (b < 42) {                        // pack_w: conv2 A-frag
    int i = b * 256 + t;
    if (i < 10752) {
      int j = i & 7, l = (i >> 3) & 63, g = (i >> 9) % 7, lvl = i / 3584;
      int oc = l & 15, sg = l >> 4;
      int s = g * 4 + sg;
      float v = 0.f;
      if (s < 25) v = cw1[((size_t)(lvl * 16 + oc) * 8 + j) * 25 + s];
      packA[i] = f2bf(v);
    }
    return;
  }
  if (b < 54) {                        // pack_w1: conv1 COL-SHIFT A-frag (R11-verified mapping)
    int i = (b - 42) * 256 + t;
    if (i < 3072) {
      int j = i & 7, lane = (i >> 3) & 63, gg = (i >> 9) & 1, lvl = i >> 10;
      int m = lane & 15, q = lane >> 4;
      int u = gg * 4 + q;
      int oc = m & 7;
      float v = 0.f;
      if (u < 5) {
        if (m < 8) { if (j < 5) v = cw0[((size_t)(lvl * 8 + oc)) * 25 + u * 5 + j]; }
        else       { if (j >= 1 && j <= 5) v = cw0[((size_t)(lvl * 8 + oc)) * 25 + u * 5 + (j - 1)]; }
      }
      packW1[i] = f2bf(v);
    }
    return;
  }
  if (b < 72) {                        // pack WgT
    int i = (b - 54) * 256 + t;
    if (i < 2048) {
      int n = i >> 5, k = i & 31;
      WgT[i] = f2bf(Wg0[k * 64 + n]);
    } else if (i < 4096) {
      int j = i - 2048, n = j >> 6, k = j & 63;
      WgT[i] = f2bf(Wg1[k * 32 + n]);
    } else if (i < 4608) {
      int j = i - 4096, n = j >> 5, k = j & 31;
      WgT[i] = f2bf(Wg2[k * 16 + n]);
    }
    return;
  }
  {                                    // pack_wl0: Wl0 -> bf16 WT[n][k]
    int bb = b - 72;                   // 768 blocks: 192 kb x 4 nb
    const int kb = (bb % 192) * 64;
    const int nb = (bb / 192) * 64;
#pragma unroll
    for (int i = 0; i < 16; ++i) {
      int idx = i * 256 + t, kk = idx >> 6, nn = idx & 63;
      tile[kk][nn] = Wl0[(size_t)(kb + kk) * 256 + nb + nn];
    }
    __syncthreads();
#pragma unroll
    for (int i = 0; i < 16; ++i) {
      int idx = i * 256 + t, nn = idx >> 6, kk = idx & 63;
      WT[(size_t)(nb + nn) * 12288 + kb + kk] = f2bf(tile[kk][nn]);
    }
  }
}

// ----------------------------- fused sim + conv1 + conv2 ------------------------------------------------
// R13 structure (single cp copy, stride 80, col-shift conv1) with ONE isolated change:
// sim MFMA operands read directly from global (bf16 k-contiguous) — no qbf/cbf staging, one less barrier.
template<int F>
__device__ __forceinline__ void sim_mfma(const unsigned short* __restrict__ qf,
    const unsigned short* __restrict__ cf, unsigned short* cp, int g, int tid)
{
  // zero cp: 72*80 = 5760 u16 = 2880 u32
  {
    unsigned int* z = reinterpret_cast<unsigned int*>(cp);
    for (int i = tid; i < 2880; i += 256) z[i] = 0u;
  }

  const int lane = tid & 63, wave = tid >> 6;
  const int c = lane & 15, q = lane >> 4;
  constexpr int NK = (F == 64) ? 2 : 1;
  const unsigned short* qg = qf + (size_t)g * 64 * F;
  const unsigned short* cg = cf + (size_t)g * 64 * F;
  const bool zlane = (F == 16) && (q >= 2);   // k>=16 slots are zero for F=16 (also avoids OOB tail read)
  const s16x8 zz8 = {0, 0, 0, 0, 0, 0, 0, 0};

  f32x4 acc[4];
#pragma unroll
  for (int nt = 0; nt < 4; ++nt) acc[nt] = (f32x4){0.f, 0.f, 0.f, 0.f};
#pragma unroll
  for (int ks = 0; ks < NK; ++ks) {
    s16x8 af = zlane ? zz8
        : *reinterpret_cast<const s16x8*>(qg + (wave * 16 + c) * F + ks * 32 + q * 8);
#pragma unroll
    for (int nt = 0; nt < 4; ++nt) {
      s16x8 bf = zlane ? zz8
          : *reinterpret_cast<const s16x8*>(cg + (nt * 16 + c) * F + ks * 32 + q * 8);
      acc[nt] = __builtin_amdgcn_mfma_f32_16x16x32_bf16(af, bf, acc[nt], 0, 0, 0);
    }
  }
  __syncthreads();   // zeroing complete before D-writes

  // D: image row i = wave*16 + q*4 + r, image col n = nt*16 + c -> cp[(i+2)*80 + n+2]
#pragma unroll
  for (int nt = 0; nt < 4; ++nt)
#pragma unroll
    for (int r = 0; r < 4; ++r)
      cp[(wave * 16 + q * 4 + r + 2) * 80 + nt * 16 + c + 2] = f2bf(acc[nt][r]);
  __syncthreads();
}

// conv1 via MFMA, col-shift variant pair (R13-verified: dword base P)
__device__ __forceinline__ void conv1_mfma(const unsigned short* cp,
    unsigned short* p1u, const unsigned short* __restrict__ packW1,
    const float* __restrict__ cb0, int lvl, int tid)
{
  const int lane = tid & 63, wave = tid >> 6;
  const int c = lane & 15, q = lane >> 4;

  // zero p1ci halo frame (272 cells, strided)
  for (int h = tid; h < 272; h += 256) {
    int r, cc;
    if (h < 72)       { r = h / 36;             cc = h % 36; }
    else if (h < 144) { r = 34 + (h - 72) / 36; cc = (h - 72) % 36; }
    else { int z = h - 144; r = 2 + (z >> 2); int wq = z & 3; cc = (wq < 2) ? wq : 32 + wq; }
    s16x8 zz = {0, 0, 0, 0, 0, 0, 0, 0};
    *reinterpret_cast<s16x8*>(p1u + (r * 36 + cc) * 8) = zz;
  }

  s16x8 aw0 = *reinterpret_cast<const s16x8*>(packW1 + ((size_t)(lvl * 2 + 0) * 64 + lane) * 8);
  s16x8 aw1 = *reinterpret_cast<const s16x8*>(packW1 + ((size_t)(lvl * 2 + 1) * 64 + lane) * 8);
  float bias[4];
#pragma unroll
  for (int r = 0; r < 4; ++r) bias[r] = cb0[lvl * 8 + (q & 1) * 4 + r];

  const unsigned int* b32 = reinterpret_cast<const unsigned int*>(cp);

  for (int pp = 0; pp < 8; ++pp) {
    const int Y = wave * 8 + pp;          // pooled row
    const int y0 = 2 * Y;
#pragma unroll
    for (int Xi = 0; Xi < 2; ++Xi) {
      const int P = Xi * 16 + c;          // pooled col; even pixel x0 = 2P; window u16 [2P,2P+8) = dwords [P,P+4)
      const int col = P;
      const int r00 = (y0 + q) * 40 + col;
      const int r01 = (y0 + 4 + q) * 40 + col;
      const int r10 = (y0 + 1 + q) * 40 + col;
      const int r11 = (y0 + 5 + q) * 40 + col;
      union { unsigned int w[4]; s16x8 v; } f00, f01, f10, f11;
#pragma unroll
      for (int k = 0; k < 4; ++k) {
        f00.w[k] = b32[r00 + k]; f01.w[k] = b32[r01 + k];
        f10.w[k] = b32[r10 + k]; f11.w[k] = b32[r11 + k];
      }
      f32x4 a0 = {0.f, 0.f, 0.f, 0.f}, a1 = {0.f, 0.f, 0.f, 0.f};
      a0 = __builtin_amdgcn_mfma_f32_16x16x32_bf16(aw0, f00.v, a0, 0, 0, 0);
      a0 = __builtin_amdgcn_mfma_f32_16x16x32_bf16(aw1, f01.v, a0, 0, 0, 0);
      a1 = __builtin_amdgcn_mfma_f32_16x16x32_bf16(aw0, f10.v, a1, 0, 0, 0);
      a1 = __builtin_amdgcn_mfma_f32_16x16x32_bf16(aw1, f11.v, a1, 0, 0, 0);
      // pool: ALL lanes compute (convergent shuffles); stores predicated
      float pv[4];
#pragma unroll
      for (int r = 0; r < 4; ++r) {
        float vm = fmaxf(a0[r], a1[r]);             // vertical pool (register)
        float hp = fmaxf(vm, __shfl_xor(vm, 32));   // horizontal pool (x <-> x+1)
        pv[r] = fmaxf(hp + bias[r], 0.f);
      }
      if (q < 2) {
        unsigned short pk[4];
#pragma unroll
        for (int r = 0; r < 4; ++r) pk[r] = f2bf(pv[r]);
        unsigned int w0 = (unsigned int)pk[0] | ((unsigned int)pk[1] << 16);
        unsigned int w1 = (unsigned int)pk[2] | ((unsigned int)pk[3] << 16);
        *reinterpret_cast<uint2*>(p1u + (((Y + 2) * 36) + (P + 2)) * 8 + q * 4) =
            make_uint2(w0, w1);
      }
    }
  }
  __syncthreads();
}

__global__ __launch_bounds__(256) void simconv_kernel(
    const unsigned short* __restrict__ qf0, const unsigned short* __restrict__ qf1,
    const unsigned short* __restrict__ qf2, const unsigned short* __restrict__ cf0,
    const unsigned short* __restrict__ cf1, const unsigned short* __restrict__ cf2,
    const float* __restrict__ cb0, const float* __restrict__ cb1,
    const unsigned short* __restrict__ packA, const unsigned short* __restrict__ packW1,
    unsigned short* __restrict__ hcat)
{
  __shared__ __align__(16) unsigned short smem[16128];   // 32256 B -> 5 blocks/CU
  // p1u [0,10368) conv1->conv2 ; cp [10368,16128) = 72x80 sim->conv1
  unsigned short* p1u = smem;
  unsigned short* cp  = smem + 10368;

  const int g = blockIdx.x, lvl = blockIdx.y, tid = threadIdx.x;

  if (lvl == 0)      sim_mfma<64>(qf0, cf0, cp, g, tid);
  else if (lvl == 1) sim_mfma<32>(qf1, cf1, cp, g, tid);
  else               sim_mfma<16>(qf2, cf2, cp, g, tid);

  conv1_mfma(cp, p1u, packW1, cb0, lvl, tid);

  // ---- conv2 via MFMA + in-register 2x2 pool -> bf16 hcat (unchanged, verified) ----
  {
    const int lane = tid & 63, wave = tid >> 6;
    const int col = lane & 15, q = lane >> 4;

    s16x8 afr[7];
#pragma unroll
    for (int gg = 0; gg < 7; ++gg)
      afr[gg] = *reinterpret_cast<const s16x8*>(packA + ((size_t)(lvl * 7 + gg) * 64 + lane) * 8);

    int off[7];
#pragma unroll
    for (int gg = 0; gg < 7; ++gg) {
      int s = gg * 4 + q; if (s > 24) s = 24;
      off[gg] = (s / 5) * 288 + (s % 5) * 8;
    }
    float bias2[4];
#pragma unroll
    for (int r = 0; r < 4; ++r) bias2[r] = cb1[lvl * 16 + q * 4 + r];

    for (int pq = 0; pq < 4; ++pq) {
      const int py = wave * 4 + pq;
#pragma unroll
      for (int h = 0; h < 2; ++h) {
        const int base0 = (2 * py) * 288 + h * 128 + col * 8;
        const int base1 = base0 + 288;
        f32x4 a0 = {0.f, 0.f, 0.f, 0.f}, a1 = {0.f, 0.f, 0.f, 0.f};
#pragma unroll
        for (int gg = 0; gg < 7; ++gg) {
          s16x8 b0 = *reinterpret_cast<const s16x8*>(p1u + base0 + off[gg]);
          a0 = __builtin_amdgcn_mfma_f32_16x16x32_bf16(afr[gg], b0, a0, 0, 0, 0);
          s16x8 b1 = *reinterpret_cast<const s16x8*>(p1u + base1 + off[gg]);
          a1 = __builtin_amdgcn_mfma_f32_16x16x32_bf16(afr[gg], b1, a1, 0, 0, 0);
        }
        float val[4];
#pragma unroll
        for (int r = 0; r < 4; ++r) {
          float vm = fmaxf(a0[r], a1[r]);
          float hp = fmaxf(vm, __shfl_xor(vm, 1));
          val[r] = fmaxf(hp + bias2[r], 0.f);
        }
        if ((col & 1) == 0) {
          int px = h * 8 + (col >> 1);
#pragma unroll
          for (int r = 0; r < 4; ++r)
            hcat[((size_t)g * 48 + lvl * 16 + q * 4 + r) * 256 + py * 16 + px] = f2bf(val[r]);
        }
      }
    }
  }
}

// ----------------------------- linear 0 via MFMA: non-atomic split-K partials (unchanged) ---------------
__global__ __launch_bounds__(256) void lin0_kernel(
    const unsigned short* __restrict__ A, const unsigned short* __restrict__ WT,
    float* __restrict__ part)
{
  __shared__ __align__(16) unsigned short sAb[64 * 72];
  __shared__ __align__(16) unsigned short sBb[64 * 72];
  const int rb = blockIdx.x * 64;
  const int cb = blockIdx.y * 64;
  const int k0 = blockIdx.z * 768;
  const int tid = threadIdx.x;
  const int lane = tid & 63, wave = tid >> 6;
  const int wm = wave >> 1, wn = wave & 1;
  const int c = lane & 15, kg = lane >> 4;
  const int srow = tid >> 2;
  const int skq  = (tid & 3) * 16;

  f32x4 acc[2][2];
#pragma unroll
  for (int i = 0; i < 2; ++i)
#pragma unroll
    for (int j = 0; j < 2; ++j) acc[i][j] = (f32x4){0.f, 0.f, 0.f, 0.f};

  for (int kt = 0; kt < 768; kt += 64) {
    {
      const unsigned short* src = A + (size_t)(rb + srow) * 12288 + k0 + kt + skq;
      s16x8 a0 = *reinterpret_cast<const s16x8*>(src);
      s16x8 a1 = *reinterpret_cast<const s16x8*>(src + 8);
      *reinterpret_cast<s16x8*>(sAb + srow * 72 + skq)     = a0;
      *reinterpret_cast<s16x8*>(sAb + srow * 72 + skq + 8) = a1;
    }
    {
      const unsigned short* src = WT + (size_t)(cb + srow) * 12288 + k0 + kt + skq;
      s16x8 w0 = *reinterpret_cast<const s16x8*>(src);
      s16x8 w1 = *reinterpret_cast<const s16x8*>(src + 8);
      *reinterpret_cast<s16x8*>(sBb + srow * 72 + skq)     = w0;
      *reinterpret_cast<s16x8*>(sBb + srow * 72 + skq + 8) = w1;
    }
    __syncthreads();

#pragma unroll
    for (int kb = 0; kb < 64; kb += 32) {
      s16x8 a0 = *reinterpret_cast<const s16x8*>(sAb + (wm * 32 +  0 + c) * 72 + kb + kg * 8);
      s16x8 a1 = *reinterpret_cast<const s16x8*>(sAb + (wm * 32 + 16 + c) * 72 + kb + kg * 8);
      s16x8 b0 = *reinterpret_cast<const s16x8*>(sBb + (wn * 32 +  0 + c) * 72 + kb + kg * 8);
      s16x8 b1 = *reinterpret_cast<const s16x8*>(sBb + (wn * 32 + 16 + c) * 72 + kb + kg * 8);
      acc[0][0] = __builtin_amdgcn_mfma_f32_16x16x32_bf16(a0, b0, acc[0][0], 0, 0, 0);
      acc[0][1] = __builtin_amdgcn_mfma_f32_16x16x32_bf16(a0, b1, acc[0][1], 0, 0, 0);
      acc[1][0] = __builtin_amdgcn_mfma_f32_16x16x32_bf16(a1, b0, acc[1][0], 0, 0, 0);
      acc[1][1] = __builtin_amdgcn_mfma_f32_16x16x32_bf16(a1, b1, acc[1][1], 0, 0, 0);
    }
    __syncthreads();
  }

  float* dstp = part + (size_t)blockIdx.z * 512 * 256;
#pragma unroll
  for (int i = 0; i < 2; ++i)
#pragma unroll
    for (int j = 0; j < 2; ++j)
#pragma unroll
      for (int r = 0; r < 4; ++r) {
        int row = rb + wm * 32 + i * 16 + kg * 4 + r;
        int col = cb + wn * 32 + j * 16 + c;
        dstp[(size_t)row * 256 + col] = acc[i][j][r];
      }
}

// ----------------------------- head: 16-way partial reduce + bias + relu -> lin1 -> score ---------------
__global__ __launch_bounds__(64) void head_kernel(
    const float* __restrict__ part, const float* __restrict__ bl0,
    const float* __restrict__ Wl1, const float* __restrict__ bl1,
    const float* __restrict__ Wsc, const float* __restrict__ bsc, float* __restrict__ out)
{
  __shared__ float sr[256];
  const int b = blockIdx.x, j = threadIdx.x;
  {
    float4 s = *reinterpret_cast<const float4*>(bl0 + j * 4);
#pragma unroll
    for (int z = 0; z < 16; ++z) {
      float4 p = *reinterpret_cast<const float4*>(part + ((size_t)z * 512 + b) * 256 + j * 4);
      s.x += p.x; s.y += p.y; s.z += p.z; s.w += p.w;
    }
    sr[j * 4 + 0] = fmaxf(s.x, 0.f);
    sr[j * 4 + 1] = fmaxf(s.y, 0.f);
    sr[j * 4 + 2] = fmaxf(s.z, 0.f);
    sr[j * 4 + 3] = fmaxf(s.w, 0.f);
  }
  __syncthreads();
  float acc = bl1[j];
  for (int k = 0; k < 256; ++k) acc = fmaf(sr[k], Wl1[k * 64 + j], acc);
  float v = fmaxf(acc, 0.f) * Wsc[j];
#pragma unroll
  for (int off = 32; off > 0; off >>= 1) v += __shfl_down(v, off);
  if (j == 0) out[b] = 1.f / (1.f + expf(-(v + bsc[0])));
}

// ----------------------------- launch -----------------------------
extern "C" void kernel_launch(void* const* d_in, const int* in_sizes, int n_in,
                              void* d_out, int out_size, void* d_ws, size_t ws_size,
                              hipStream_t stream)
{
  (void)in_sizes; (void)n_in; (void)out_size; (void)ws_size;
  const float* x_q = (const float*)d_in[0];
  const float* x_c = (const float*)d_in[1];
  const int*   src_q = (const int*)d_in[2];
  const int*   dst_q = (const int*)d_in[3];
  const int*   src_c = (const int*)d_in[4];
  const int*   dst_c = (const int*)d_in[5];
  const float* Wg0 = (const float*)d_in[6];
  const float* bg0 = (const float*)d_in[7];
  const float* Wg1 = (const float*)d_in[8];
  const float* bg1 = (const float*)d_in[9];
  const float* Wg2 = (const float*)d_in[10];
  const float* bg2 = (const float*)d_in[11];
  const float* cw0 = (const float*)d_in[12];
  const float* cb0 = (const float*)d_in[13];
  const float* cw1 = (const float*)d_in[14];
  const float* cb1 = (const float*)d_in[15];
  const float* Wl0 = (const float*)d_in[16];
  const float* bl0 = (const float*)d_in[17];
  const float* Wl1 = (const float*)d_in[18];
  const float* bl1 = (const float*)d_in[19];
  const float* Wsc = (const float*)d_in[20];
  const float* bsc = (const float*)d_in[21];
  float* out = (float*)d_out;

  // workspace carve (float-granular; all u16 regions even-sized)
  float* ws = (float*)d_ws;
  unsigned short* qf0 = (unsigned short*)ws; ws += (size_t)NB * MM * 64 / 2;
  unsigned short* qf1 = (unsigned short*)ws; ws += (size_t)NB * MM * 32 / 2;
  unsigned short* qf2 = (unsigned short*)ws; ws += (size_t)NB * MM * 16 / 2;
  unsigned short* cf0 = (unsigned short*)ws; ws += (size_t)NB * MM * 64 / 2;
  unsigned short* cf1 = (unsigned short*)ws; ws += (size_t)NB * MM * 32 / 2;
  unsigned short* cf2 = (unsigned short*)ws; ws += (size_t)NB * MM * 16 / 2;
  unsigned short* hcat = (unsigned short*)ws; ws += (size_t)NB * 48 * 256 / 2;
  float* part = ws; ws += (size_t)16 * 512 * 256;              // 8.4 MB split-K partials
  unsigned short* packA  = (unsigned short*)ws; ws += 5376;    // 10752 bf16
  unsigned short* packW1 = (unsigned short*)ws; ws += 1536;    // 3072 bf16
  unsigned short* WgT    = (unsigned short*)ws; ws += 2304;    // 4608 bf16
  unsigned short* WT = (unsigned short*)ws; ws += (size_t)256 * 12288 / 2;

  prep_misc<<<840, 256, 0, stream>>>(cw1, cw0, Wg0, Wg1, Wg2, Wl0,
                                     packA, packW1, WgT, WT);

  gcn_kernel<<<dim3(NB, 2), 256, 0, stream>>>(x_q, x_c, src_q, dst_q, src_c, dst_c,
      WgT, bg0, bg1, bg2, qf0, qf1, qf2, cf0, cf1, cf2);

  simconv_kernel<<<dim3(NB, 3), 256, 0, stream>>>(qf0, qf1, qf2, cf0, cf1, cf2,
      cb0, cb1, packA, packW1, hcat);

  lin0_kernel<<<dim3(8, 4, 16), 256, 0, stream>>>(hcat, WT, part);
  head_kernel<<<NB, 64, 0, stream>>>(part, bl0, Wl1, bl1, Wsc, bsc, out);
}

// Round 16
// 78.843 us; speedup vs baseline: 1.0336x; 1.0104x over previous
//
#include <hip/hip_runtime.h>
#include <math.h>

#define NB 512      // graph pairs
#define MM 64       // nodes per graph
#define EPGc 512    // edges per graph

typedef __attribute__((ext_vector_type(8))) short s16x8;
typedef __attribute__((ext_vector_type(4))) float f32x4;

__device__ __forceinline__ unsigned short f2bf(float f) {
  union { float f; unsigned int u; } c; c.f = f;
  unsigned int u = c.u;
  return (unsigned short)((u + 0x7FFFu + ((u >> 16) & 1u)) >> 16);   // RNE
}
__device__ __forceinline__ float bf2f(unsigned short h) {
  union { unsigned int u; float f; } c; c.u = ((unsigned int)h) << 16;
  return c.f;
}

// ----------------------------- GCN via MFMA (verified R12/R13) ------------------------------------------
template<int Fin, int Fout, bool RELU>
__device__ __forceinline__ void gcn_layer_mfma(
    const unsigned short* __restrict__ WT, const float* __restrict__ bias,
    unsigned short* hbuf, unsigned short* stT, const unsigned short* Ab,
    unsigned short* __restrict__ outG, int g, int tid)
{
  const int lane = tid & 63, w = tid >> 6;
  const int c = lane & 15, q = lane >> 4;
  constexpr int NT = Fout / 16;
  constexpr int KS = Fin / 32;

  // GEMM1: st = h @ W -> stT[fout][node]
#pragma unroll
  for (int nt = 0; nt < NT; ++nt) {
    f32x4 acc = {0.f, 0.f, 0.f, 0.f};
#pragma unroll
    for (int ks = 0; ks < KS; ++ks) {
      s16x8 a = *reinterpret_cast<const s16x8*>(hbuf + (w * 16 + c) * 72 + ks * 32 + q * 8);
      s16x8 b = *reinterpret_cast<const s16x8*>(WT + (nt * 16 + c) * Fin + ks * 32 + q * 8);
      acc = __builtin_amdgcn_mfma_f32_16x16x32_bf16(a, b, acc, 0, 0, 0);
    }
    unsigned int w0 = (unsigned int)f2bf(acc[0]) | ((unsigned int)f2bf(acc[1]) << 16);
    unsigned int w1 = (unsigned int)f2bf(acc[2]) | ((unsigned int)f2bf(acc[3]) << 16);
    *reinterpret_cast<uint2*>(stT + (nt * 16 + c) * 72 + w * 16 + q * 4) = make_uint2(w0, w1);
  }
  __syncthreads();

  // GEMM2: out[f][dst] = sum_src st[src][f] * A[dst][src]
#pragma unroll
  for (int mt = 0; mt < NT; ++mt) {
    f32x4 acc = {0.f, 0.f, 0.f, 0.f};
#pragma unroll
    for (int ks = 0; ks < 2; ++ks) {
      s16x8 a = *reinterpret_cast<const s16x8*>(stT + (mt * 16 + c) * 72 + ks * 32 + q * 8);
      s16x8 b = *reinterpret_cast<const s16x8*>(Ab + (w * 16 + c) * 72 + ks * 32 + q * 8);
      acc = __builtin_amdgcn_mfma_f32_16x16x32_bf16(a, b, acc, 0, 0, 0);
    }
    const int node = w * 16 + c, f0 = mt * 16 + q * 4;
    unsigned short pk[4], pr[4];
#pragma unroll
    for (int r = 0; r < 4; ++r) {
      float v = acc[r] + bias[f0 + r];
      pk[r] = f2bf(v);
      pr[r] = f2bf(fmaxf(v, 0.f));
    }
    *reinterpret_cast<uint2*>(outG + (size_t)(g * MM + node) * Fout + f0) =
        make_uint2((unsigned int)pk[0] | ((unsigned int)pk[1] << 16),
                   (unsigned int)pk[2] | ((unsigned int)pk[3] << 16));
    if (RELU)
      *reinterpret_cast<uint2*>(hbuf + node * 72 + f0) =
          make_uint2((unsigned int)pr[0] | ((unsigned int)pr[1] << 16),
                     (unsigned int)pr[2] | ((unsigned int)pr[3] << 16));
  }
  __syncthreads();
}

__global__ __launch_bounds__(256) void gcn_kernel(
    const float* __restrict__ xq, const float* __restrict__ xc,
    const int* __restrict__ srcq, const int* __restrict__ dstq,
    const int* __restrict__ srcc, const int* __restrict__ dstc,
    const unsigned short* __restrict__ WgT,
    const float* __restrict__ bg0, const float* __restrict__ bg1, const float* __restrict__ bg2,
    unsigned short* __restrict__ qf0, unsigned short* __restrict__ qf1,
    unsigned short* __restrict__ qf2, unsigned short* __restrict__ cf0,
    unsigned short* __restrict__ cf1, unsigned short* __restrict__ cf2)
{
  __shared__ __align__(16) unsigned short smem[13824];  // hbuf|stT|Ab, each [64][72]
  __shared__ float sDinv[MM];
  __shared__ int sDeg[MM];
  unsigned short* hbuf = smem;
  unsigned short* stT  = smem + 4608;
  unsigned short* Ab   = smem + 9216;
  float* sAf = reinterpret_cast<float*>(smem);   // [64][68] fp32, aliases hbuf+stT (build phase only)

  const int g = blockIdx.x;
  const int which = blockIdx.y;
  const float* x = which ? xc : xq;
  const int* src = which ? srcc : srcq;
  const int* dst = which ? dstc : dstq;
  unsigned short* f0p = which ? cf0 : qf0;
  unsigned short* f1p = which ? cf1 : qf1;
  unsigned short* f2p = which ? cf2 : qf2;
  const int tid = threadIdx.x;

  for (int i = tid; i < 64 * 68; i += 256) sAf[i] = 0.f;
  if (tid < MM) sDeg[tid] = 1;
  __syncthreads();
  for (int e = tid; e < EPGc; e += 256)
    atomicAdd(&sDeg[dst[g * EPGc + e] - g * MM], 1);
  __syncthreads();
  if (tid < MM) sDinv[tid] = rsqrtf((float)sDeg[tid]);
  __syncthreads();
  for (int e = tid; e < EPGc; e += 256) {
    int s = src[g * EPGc + e] - g * MM;
    int d = dst[g * EPGc + e] - g * MM;
    atomicAdd(&sAf[d * 68 + s], sDinv[s] * sDinv[d]);
  }
  if (tid < MM) atomicAdd(&sAf[tid * 68 + tid], sDinv[tid] * sDinv[tid]);
  __syncthreads();
  for (int i = tid; i < 4096; i += 256) {
    int r = i >> 6, s = i & 63;
    Ab[r * 72 + s] = f2bf(sAf[r * 68 + s]);
  }
  __syncthreads();
  {
    const float* xs = x + (size_t)g * 2048 + tid * 8;
    float4 v0 = *reinterpret_cast<const float4*>(xs);
    float4 v1 = *reinterpret_cast<const float4*>(xs + 4);
    s16x8 p;
    p[0] = (short)f2bf(v0.x); p[1] = (short)f2bf(v0.y); p[2] = (short)f2bf(v0.z); p[3] = (short)f2bf(v0.w);
    p[4] = (short)f2bf(v1.x); p[5] = (short)f2bf(v1.y); p[6] = (short)f2bf(v1.z); p[7] = (short)f2bf(v1.w);
    int node = tid >> 2, k = (tid & 3) * 8;
    *reinterpret_cast<s16x8*>(hbuf + node * 72 + k) = p;
  }
  __syncthreads();

  gcn_layer_mfma<32, 64, true >(WgT,        bg0, hbuf, stT, Ab, f0p, g, tid);
  gcn_layer_mfma<64, 32, true >(WgT + 2048, bg1, hbuf, stT, Ab, f1p, g, tid);
  gcn_layer_mfma<32, 16, false>(WgT + 4096, bg2, hbuf, stT, Ab, f2p, g, tid);
}

// ----------------------------- merged prep (verified R13) ----------------------------------------------
__global__ __launch_bounds__(256) void prep_misc(
    const float* __restrict__ cw1, const float* __restrict__ cw0,
    const float* __restrict__ Wg0, const float* __restrict__ Wg1, const float* __restrict__ Wg2,
    const float* __restrict__ Wl0,
    unsigned short* __restrict__ packA, unsigned short* __restrict__ packW1,
    unsigned short* __restrict__ WgT, unsigned short* __restrict__ WT)
{
  __shared__ float tile[64][65];
  const int b = blockIdx.x, t = threadIdx.x;
  if (b < 42) {                        // pack_w: conv2 A-frag
    int i = b * 256 + t;
    if (i < 10752) {
      int j = i & 7, l = (i >> 3) & 63, g = (i >> 9) % 7, lvl = i / 3584;
      int oc = l & 15, sg = l >> 4;
      int s = g * 4 + sg;
      float v = 0.f;
      if (s < 25) v = cw1[((size_t)(lvl * 16 + oc) * 8 + j) * 25 + s];
      packA[i] = f2bf(v);
    }
    return;
  }
  if (b < 54) {                        // pack_w1: conv1 COL-SHIFT A-frag (R11-verified mapping)
    int i = (b - 42) * 256 + t;
    if (i < 3072) {
      int j = i & 7, lane = (i >> 3) & 63, gg = (i >> 9) & 1, lvl = i >> 10;
      int m = lane & 15, q = lane >> 4;
      int u = gg * 4 + q;
      int oc = m & 7;
      float v = 0.f;
      if (u < 5) {
        if (m < 8) { if (j < 5) v = cw0[((size_t)(lvl * 8 + oc)) * 25 + u * 5 + j]; }
        else       { if (j >= 1 && j <= 5) v = cw0[((size_t)(lvl * 8 + oc)) * 25 + u * 5 + (j - 1)]; }
      }
      packW1[i] = f2bf(v);
    }
    return;
  }
  if (b < 72) {                        // pack WgT
    int i = (b - 54) * 256 + t;
    if (i < 2048) {
      int n = i >> 5, k = i & 31;
      WgT[i] = f2bf(Wg0[k * 64 + n]);
    } else if (i < 4096) {
      int j = i - 2048, n = j >> 6, k = j & 63;
      WgT[i] = f2bf(Wg1[k * 32 + n]);
    } else if (i < 4608) {
      int j = i - 4096, n = j >> 5, k = j & 31;
      WgT[i] = f2bf(Wg2[k * 16 + n]);
    }
    return;
  }
  {                                    // pack_wl0: Wl0 -> bf16 WT[n][k]
    int bb = b - 72;                   // 768 blocks: 192 kb x 4 nb
    const int kb = (bb % 192) * 64;
    const int nb = (bb / 192) * 64;
#pragma unroll
    for (int i = 0; i < 16; ++i) {
      int idx = i * 256 + t, kk = idx >> 6, nn = idx & 63;
      tile[kk][nn] = Wl0[(size_t)(kb + kk) * 256 + nb + nn];
    }
    __syncthreads();
#pragma unroll
    for (int i = 0; i < 16; ++i) {
      int idx = i * 256 + t, nn = idx >> 6, kk = idx & 63;
      WT[(size_t)(nb + nn) * 12288 + kb + kk] = f2bf(tile[kk][nn]);
    }
  }
}

// ----------------------------- fused sim + conv1 + conv2 (R13-verified best) ----------------------------
template<int F>
__device__ __forceinline__ void sim_mfma(const unsigned short* __restrict__ qf,
    const unsigned short* __restrict__ cf, unsigned short* qbf, unsigned short* cbf,
    unsigned short* cp, int g, int tid)
{
  constexpr int SQ = (F == 16) ? 40 : F + 8;
  {
    unsigned int* z = reinterpret_cast<unsigned int*>(cp);
    for (int i = tid; i < 2880; i += 256) z[i] = 0u;
  }
  for (int i = tid; i < 64 * F / 8; i += 256) {
    int row = (i * 8) / F, k = (i * 8) % F;
    s16x8 qv = *reinterpret_cast<const s16x8*>(qf + (size_t)g * 64 * F + i * 8);
    s16x8 cv = *reinterpret_cast<const s16x8*>(cf + (size_t)g * 64 * F + i * 8);
    *reinterpret_cast<s16x8*>(qbf + row * SQ + k) = qv;
    *reinterpret_cast<s16x8*>(cbf + row * SQ + k) = cv;
  }
  if (F == 16) {
    for (int i = tid; i < 128; i += 256) {
      int row = i >> 1, h = (i & 1) * 8;
      s16x8 zz = {0, 0, 0, 0, 0, 0, 0, 0};
      *reinterpret_cast<s16x8*>(qbf + row * SQ + 16 + h) = zz;
      *reinterpret_cast<s16x8*>(cbf + row * SQ + 16 + h) = zz;
    }
  }
  __syncthreads();

  const int lane = tid & 63, wave = tid >> 6;
  const int c = lane & 15, q = lane >> 4;
  constexpr int NK = (F == 64) ? 2 : 1;

  f32x4 acc[4];
#pragma unroll
  for (int nt = 0; nt < 4; ++nt) acc[nt] = (f32x4){0.f, 0.f, 0.f, 0.f};
#pragma unroll
  for (int ks = 0; ks < NK; ++ks) {
    s16x8 af = *reinterpret_cast<const s16x8*>(qbf + (wave * 16 + c) * SQ + ks * 32 + q * 8);
#pragma unroll
    for (int nt = 0; nt < 4; ++nt) {
      s16x8 bf = *reinterpret_cast<const s16x8*>(cbf + (nt * 16 + c) * SQ + ks * 32 + q * 8);
      acc[nt] = __builtin_amdgcn_mfma_f32_16x16x32_bf16(af, bf, acc[nt], 0, 0, 0);
    }
  }
#pragma unroll
  for (int nt = 0; nt < 4; ++nt)
#pragma unroll
    for (int r = 0; r < 4; ++r)
      cp[(wave * 16 + q * 4 + r + 2) * 80 + nt * 16 + c + 2] = f2bf(acc[nt][r]);
  __syncthreads();
}

// conv1 via MFMA, col-shift variant pair (R13-verified: dword base P)
__device__ __forceinline__ void conv1_mfma(const unsigned short* cp,
    unsigned short* p1u, const unsigned short* __restrict__ packW1,
    const float* __restrict__ cb0, int lvl, int tid)
{
  const int lane = tid & 63, wave = tid >> 6;
  const int c = lane & 15, q = lane >> 4;

  for (int h = tid; h < 272; h += 256) {
    int r, cc;
    if (h < 72)       { r = h / 36;             cc = h % 36; }
    else if (h < 144) { r = 34 + (h - 72) / 36; cc = (h - 72) % 36; }
    else { int z = h - 144; r = 2 + (z >> 2); int wq = z & 3; cc = (wq < 2) ? wq : 32 + wq; }
    s16x8 zz = {0, 0, 0, 0, 0, 0, 0, 0};
    *reinterpret_cast<s16x8*>(p1u + (r * 36 + cc) * 8) = zz;
  }

  s16x8 aw0 = *reinterpret_cast<const s16x8*>(packW1 + ((size_t)(lvl * 2 + 0) * 64 + lane) * 8);
  s16x8 aw1 = *reinterpret_cast<const s16x8*>(packW1 + ((size_t)(lvl * 2 + 1) * 64 + lane) * 8);
  float bias[4];
#pragma unroll
  for (int r = 0; r < 4; ++r) bias[r] = cb0[lvl * 8 + (q & 1) * 4 + r];

  const unsigned int* b32 = reinterpret_cast<const unsigned int*>(cp);

  for (int pp = 0; pp < 8; ++pp) {
    const int Y = wave * 8 + pp;
    const int y0 = 2 * Y;
#pragma unroll
    for (int Xi = 0; Xi < 2; ++Xi) {
      const int P = Xi * 16 + c;
      const int col = P;
      const int r00 = (y0 + q) * 40 + col;
      const int r01 = (y0 + 4 + q) * 40 + col;
      const int r10 = (y0 + 1 + q) * 40 + col;
      const int r11 = (y0 + 5 + q) * 40 + col;
      union { unsigned int w[4]; s16x8 v; } f00, f01, f10, f11;
#pragma unroll
      for (int k = 0; k < 4; ++k) {
        f00.w[k] = b32[r00 + k]; f01.w[k] = b32[r01 + k];
        f10.w[k] = b32[r10 + k]; f11.w[k] = b32[r11 + k];
      }
      f32x4 a0 = {0.f, 0.f, 0.f, 0.f}, a1 = {0.f, 0.f, 0.f, 0.f};
      a0 = __builtin_amdgcn_mfma_f32_16x16x32_bf16(aw0, f00.v, a0, 0, 0, 0);
      a0 = __builtin_amdgcn_mfma_f32_16x16x32_bf16(aw1, f01.v, a0, 0, 0, 0);
      a1 = __builtin_amdgcn_mfma_f32_16x16x32_bf16(aw0, f10.v, a1, 0, 0, 0);
      a1 = __builtin_amdgcn_mfma_f32_16x16x32_bf16(aw1, f11.v, a1, 0, 0, 0);
      float pv[4];
#pragma unroll
      for (int r = 0; r < 4; ++r) {
        float vm = fmaxf(a0[r], a1[r]);
        float hp = fmaxf(vm, __shfl_xor(vm, 32));
        pv[r] = fmaxf(hp + bias[r], 0.f);
      }
      if (q < 2) {
        unsigned short pk[4];
#pragma unroll
        for (int r = 0; r < 4; ++r) pk[r] = f2bf(pv[r]);
        unsigned int w0 = (unsigned int)pk[0] | ((unsigned int)pk[1] << 16);
        unsigned int w1 = (unsigned int)pk[2] | ((unsigned int)pk[3] << 16);
        *reinterpret_cast<uint2*>(p1u + (((Y + 2) * 36) + (P + 2)) * 8 + q * 4) =
            make_uint2(w0, w1);
      }
    }
  }
  __syncthreads();
}

__global__ __launch_bounds__(256) void simconv_kernel(
    const unsigned short* __restrict__ qf0, const unsigned short* __restrict__ qf1,
    const unsigned short* __restrict__ qf2, const unsigned short* __restrict__ cf0,
    const unsigned short* __restrict__ cf1, const unsigned short* __restrict__ cf2,
    const float* __restrict__ cb0, const float* __restrict__ cb1,
    const unsigned short* __restrict__ packA, const unsigned short* __restrict__ packW1,
    unsigned short* __restrict__ hcat)
{
  __shared__ __align__(16) unsigned short smem[16128];   // 32256 B -> 5 blocks/CU
  unsigned short* qbf = smem;
  unsigned short* cbf = smem + 4608;
  unsigned short* p1u = smem;
  unsigned short* cp  = smem + 10368;

  const int g = blockIdx.x, lvl = blockIdx.y, tid = threadIdx.x;

  if (lvl == 0)      sim_mfma<64>(qf0, cf0, qbf, cbf, cp, g, tid);
  else if (lvl == 1) sim_mfma<32>(qf1, cf1, qbf, cbf, cp, g, tid);
  else               sim_mfma<16>(qf2, cf2, qbf, cbf, cp, g, tid);

  conv1_mfma(cp, p1u, packW1, cb0, lvl, tid);

  // ---- conv2 via MFMA + in-register 2x2 pool -> bf16 hcat ----
  {
    const int lane = tid & 63, wave = tid >> 6;
    const int col = lane & 15, q = lane >> 4;

    s16x8 afr[7];
#pragma unroll
    for (int gg = 0; gg < 7; ++gg)
      afr[gg] = *reinterpret_cast<const s16x8*>(packA + ((size_t)(lvl * 7 + gg) * 64 + lane) * 8);

    int off[7];
#pragma unroll
    for (int gg = 0; gg < 7; ++gg) {
      int s = gg * 4 + q; if (s > 24) s = 24;
      off[gg] = (s / 5) * 288 + (s % 5) * 8;
    }
    float bias2[4];
#pragma unroll
    for (int r = 0; r < 4; ++r) bias2[r] = cb1[lvl * 16 + q * 4 + r];

    for (int pq = 0; pq < 4; ++pq) {
      const int py = wave * 4 + pq;
#pragma unroll
      for (int h = 0; h < 2; ++h) {
        const int base0 = (2 * py) * 288 + h * 128 + col * 8;
        const int base1 = base0 + 288;
        f32x4 a0 = {0.f, 0.f, 0.f, 0.f}, a1 = {0.f, 0.f, 0.f, 0.f};
#pragma unroll
        for (int gg = 0; gg < 7; ++gg) {
          s16x8 b0 = *reinterpret_cast<const s16x8*>(p1u + base0 + off[gg]);
          a0 = __builtin_amdgcn_mfma_f32_16x16x32_bf16(afr[gg], b0, a0, 0, 0, 0);
          s16x8 b1 = *reinterpret_cast<const s16x8*>(p1u + base1 + off[gg]);
          a1 = __builtin_amdgcn_mfma_f32_16x16x32_bf16(afr[gg], b1, a1, 0, 0, 0);
        }
        float val[4];
#pragma unroll
        for (int r = 0; r < 4; ++r) {
          float vm = fmaxf(a0[r], a1[r]);
          float hp = fmaxf(vm, __shfl_xor(vm, 1));
          val[r] = fmaxf(hp + bias2[r], 0.f);
        }
        if ((col & 1) == 0) {
          int px = h * 8 + (col >> 1);
#pragma unroll
          for (int r = 0; r < 4; ++r)
            hcat[((size_t)g * 48 + lvl * 16 + q * 4 + r) * 256 + py * 16 + px] = f2bf(val[r]);
        }
      }
    }
  }
}

// ----------------------------- linear 0 via MFMA: non-atomic split-K partials ---------------------------
__global__ __launch_bounds__(256) void lin0_kernel(
    const unsigned short* __restrict__ A, const unsigned short* __restrict__ WT,
    float* __restrict__ part)
{
  __shared__ __align__(16) unsigned short sAb[64 * 72];
  __shared__ __align__(16) unsigned short sBb[64 * 72];
  const int rb = blockIdx.x * 64;
  const int cb = blockIdx.y * 64;
  const int k0 = blockIdx.z * 768;
  const int tid = threadIdx.x;
  const int lane = tid & 63, wave = tid >> 6;
  const int wm = wave >> 1, wn = wave & 1;
  const int c = lane & 15, kg = lane >> 4;
  const int srow = tid >> 2;
  const int skq  = (tid & 3) * 16;

  f32x4 acc[2][2];
#pragma unroll
  for (int i = 0; i < 2; ++i)
#pragma unroll
    for (int j = 0; j < 2; ++j) acc[i][j] = (f32x4){0.f, 0.f, 0.f, 0.f};

  for (int kt = 0; kt < 768; kt += 64) {
    {
      const unsigned short* src = A + (size_t)(rb + srow) * 12288 + k0 + kt + skq;
      s16x8 a0 = *reinterpret_cast<const s16x8*>(src);
      s16x8 a1 = *reinterpret_cast<const s16x8*>(src + 8);
      *reinterpret_cast<s16x8*>(sAb + srow * 72 + skq)     = a0;
      *reinterpret_cast<s16x8*>(sAb + srow * 72 + skq + 8) = a1;
    }
    {
      const unsigned short* src = WT + (size_t)(cb + srow) * 12288 + k0 + kt + skq;
      s16x8 w0 = *reinterpret_cast<const s16x8*>(src);
      s16x8 w1 = *reinterpret_cast<const s16x8*>(src + 8);
      *reinterpret_cast<s16x8*>(sBb + srow * 72 + skq)     = w0;
      *reinterpret_cast<s16x8*>(sBb + srow * 72 + skq + 8) = w1;
    }
    __syncthreads();

#pragma unroll
    for (int kb = 0; kb < 64; kb += 32) {
      s16x8 a0 = *reinterpret_cast<const s16x8*>(sAb + (wm * 32 +  0 + c) * 72 + kb + kg * 8);
      s16x8 a1 = *reinterpret_cast<const s16x8*>(sAb + (wm * 32 + 16 + c) * 72 + kb + kg * 8);
      s16x8 b0 = *reinterpret_cast<const s16x8*>(sBb + (wn * 32 +  0 + c) * 72 + kb + kg * 8);
      s16x8 b1 = *reinterpret_cast<const s16x8*>(sBb + (wn * 32 + 16 + c) * 72 + kb + kg * 8);
      acc[0][0] = __builtin_amdgcn_mfma_f32_16x16x32_bf16(a0, b0, acc[0][0], 0, 0, 0);
      acc[0][1] = __builtin_amdgcn_mfma_f32_16x16x32_bf16(a0, b1, acc[0][1], 0, 0, 0);
      acc[1][0] = __builtin_amdgcn_mfma_f32_16x16x32_bf16(a1, b0, acc[1][0], 0, 0, 0);
      acc[1][1] = __builtin_amdgcn_mfma_f32_16x16x32_bf16(a1, b1, acc[1][1], 0, 0, 0);
    }
    __syncthreads();
  }

  float* dstp = part + (size_t)blockIdx.z * 512 * 256;
#pragma unroll
  for (int i = 0; i < 2; ++i)
#pragma unroll
    for (int j = 0; j < 2; ++j)
#pragma unroll
      for (int r = 0; r < 4; ++r) {
        int row = rb + wm * 32 + i * 16 + kg * 4 + r;
        int col = cb + wn * 32 + j * 16 + c;
        dstp[(size_t)row * 256 + col] = acc[i][j][r];
      }
}

// ----------------------------- head: 16-way partial reduce + bias + relu -> lin1 -> score ---------------
__global__ __launch_bounds__(64) void head_kernel(
    const float* __restrict__ part, const float* __restrict__ bl0,
    const float* __restrict__ Wl1, const float* __restrict__ bl1,
    const float* __restrict__ Wsc, const float* __restrict__ bsc, float* __restrict__ out)
{
  __shared__ float sr[256];
  const int b = blockIdx.x, j = threadIdx.x;
  {
    float4 s = *reinterpret_cast<const float4*>(bl0 + j * 4);
#pragma unroll
    for (int z = 0; z < 16; ++z) {
      float4 p = *reinterpret_cast<const float4*>(part + ((size_t)z * 512 + b) * 256 + j * 4);
      s.x += p.x; s.y += p.y; s.z += p.z; s.w += p.w;
    }
    sr[j * 4 + 0] = fmaxf(s.x, 0.f);
    sr[j * 4 + 1] = fmaxf(s.y, 0.f);
    sr[j * 4 + 2] = fmaxf(s.z, 0.f);
    sr[j * 4 + 3] = fmaxf(s.w, 0.f);
  }
  __syncthreads();
  float acc = bl1[j];
  for (int k = 0; k < 256; ++k) acc = fmaf(sr[k], Wl1[k * 64 + j], acc);
  float v = fmaxf(acc, 0.f) * Wsc[j];
#pragma unroll
  for (int off = 32; off > 0; off >>= 1) v += __shfl_down(v, off);
  if (j == 0) out[b] = 1.f / (1.f + expf(-(v + bsc[0])));
}

// ----------------------------- launch -----------------------------
extern "C" void kernel_launch(void* const* d_in, const int* in_sizes, int n_in,
                              void* d_out, int out_size, void* d_ws, size_t ws_size,
                              hipStream_t stream)
{
  (void)in_sizes; (void)n_in; (void)out_size; (void)ws_size;
  const float* x_q = (const float*)d_in[0];
  const float* x_c = (const float*)d_in[1];
  const int*   src_q = (const int*)d_in[2];
  const int*   dst_q = (const int*)d_in[3];
  const int*   src_c = (const int*)d_in[4];
  const int*   dst_c = (const int*)d_in[5];
  const float* Wg0 = (const float*)d_in[6];
  const float* bg0 = (const float*)d_in[7];
  const float* Wg1 = (const float*)d_in[8];
  const float* bg1 = (const float*)d_in[9];
  const float* Wg2 = (const float*)d_in[10];
  const float* bg2 = (const float*)d_in[11];
  const float* cw0 = (const float*)d_in[12];
  const float* cb0 = (const float*)d_in[13];
  const float* cw1 = (const float*)d_in[14];
  const float* cb1 = (const float*)d_in[15];
  const float* Wl0 = (const float*)d_in[16];
  const float* bl0 = (const float*)d_in[17];
  const float* Wl1 = (const float*)d_in[18];
  const float* bl1 = (const float*)d_in[19];
  const float* Wsc = (const float*)d_in[20];
  const float* bsc = (const float*)d_in[21];
  float* out = (float*)d_out;

  // workspace carve (float-granular; all u16 regions even-sized)
  float* ws = (float*)d_ws;
  unsigned short* qf0 = (unsigned short*)ws; ws += (size_t)NB * MM * 64 / 2;
  unsigned short* qf1 = (unsigned short*)ws; ws += (size_t)NB * MM * 32 / 2;
  unsigned short* qf2 = (unsigned short*)ws; ws += (size_t)NB * MM * 16 / 2;
  unsigned short* cf0 = (unsigned short*)ws; ws += (size_t)NB * MM * 64 / 2;
  unsigned short* cf1 = (unsigned short*)ws; ws += (size_t)NB * MM * 32 / 2;
  unsigned short* cf2 = (unsigned short*)ws; ws += (size_t)NB * MM * 16 / 2;
  unsigned short* hcat = (unsigned short*)ws; ws += (size_t)NB * 48 * 256 / 2;
  float* part = ws; ws += (size_t)16 * 512 * 256;              // 8.4 MB split-K partials
  unsigned short* packA  = (unsigned short*)ws; ws += 5376;    // 10752 bf16
  unsigned short* packW1 = (unsigned short*)ws; ws += 1536;    // 3072 bf16
  unsigned short* WgT    = (unsigned short*)ws; ws += 2304;    // 4608 bf16
  unsigned short* WT = (unsigned short*)ws; ws += (size_t)256 * 12288 / 2;

  prep_misc<<<840, 256, 0, stream>>>(cw1, cw0, Wg0, Wg1, Wg2, Wl0,
                                     packA, packW1, WgT, WT);

  gcn_kernel<<<dim3(NB, 2), 256, 0, stream>>>(x_q, x_c, src_q, dst_q, src_c, dst_c,
      WgT, bg0, bg1, bg2, qf0, qf1, qf2, cf0, cf1, cf2);

  simconv_kernel<<<dim3(NB, 3), 256, 0, stream>>>(qf0, qf1, qf2, cf0, cf1, cf2,
      cb0, cb1, packA, packW1, hcat);

  lin0_kernel<<<dim3(8, 4, 16), 256, 0, stream>>>(hcat, WT, part);
  head_kernel<<<NB, 64, 0, stream>>>(part, bl0, Wl1, bl1, Wsc, bsc, out);
}